// Round 1
// baseline (204.977 us; speedup 1.0000x reference)
//
#include <hip/hip_runtime.h>

#define H  256
#define W  256
#define S  4
#define OH (H * S)
#define OW (W * S)

__global__ __launch_bounds__(256) void bicubic_up4(
    const float* __restrict__ x, const float* __restrict__ kern,
    float* __restrict__ out)
{
    const int iw = threadIdx.x;   // input column 0..255
    const int ih = blockIdx.x;    // input row    0..255
    const int nc = blockIdx.y;    // n*c          0..47

    // 16 filter taps (4 phases x 4 taps) — uniform, scalar-cached
    float kk[16];
#pragma unroll
    for (int i = 0; i < 16; ++i) kk[i] = kern[i];

    const float* __restrict__ xp = x + (size_t)nc * (H * W);

    // replicate-pad == clamp: taps at ih-1..ih+2, iw-1..iw+2
    const int r0 = max(ih - 1, 0);
    const int r1 = ih;
    const int r2 = min(ih + 1, H - 1);
    const int r3 = min(ih + 2, H - 1);
    const int c0 = max(iw - 1, 0);
    const int c1 = iw;
    const int c2 = min(iw + 1, W - 1);
    const int c3 = min(iw + 2, W - 1);

    float p[4][4];
    {
        const int rr[4] = { r0, r1, r2, r3 };
        const int cc[4] = { c0, c1, c2, c3 };
#pragma unroll
        for (int j = 0; j < 4; ++j) {
            const float* row = xp + rr[j] * W;
#pragma unroll
            for (int i = 0; i < 4; ++i)
                p[j][i] = row[cc[i]];
        }
    }

    float* __restrict__ op =
        out + ((size_t)nc * OH + (size_t)ih * S) * OW + (size_t)iw * S;

#pragma unroll
    for (int kv = 0; kv < 4; ++kv) {
        const float w0 = kk[kv * 4 + 0];
        const float w1 = kk[kv * 4 + 1];
        const float w2 = kk[kv * 4 + 2];
        const float w3 = kk[kv * 4 + 3];
        // vertical pass at the 4 tap columns
        const float v0 = p[0][0] * w0 + p[1][0] * w1 + p[2][0] * w2 + p[3][0] * w3;
        const float v1 = p[0][1] * w0 + p[1][1] * w1 + p[2][1] * w2 + p[3][1] * w3;
        const float v2 = p[0][2] * w0 + p[1][2] * w1 + p[2][2] * w2 + p[3][2] * w3;
        const float v3 = p[0][3] * w0 + p[1][3] * w1 + p[2][3] * w2 + p[3][3] * w3;
        // horizontal pass: 4 output phases
        float4 o;
        o.x = v0 * kk[0]  + v1 * kk[1]  + v2 * kk[2]  + v3 * kk[3];
        o.y = v0 * kk[4]  + v1 * kk[5]  + v2 * kk[6]  + v3 * kk[7];
        o.z = v0 * kk[8]  + v1 * kk[9]  + v2 * kk[10] + v3 * kk[11];
        o.w = v0 * kk[12] + v1 * kk[13] + v2 * kk[14] + v3 * kk[15];
        *reinterpret_cast<float4*>(op + (size_t)kv * OW) = o;
    }
}

extern "C" void kernel_launch(void* const* d_in, const int* in_sizes, int n_in,
                              void* d_out, int out_size, void* d_ws, size_t ws_size,
                              hipStream_t stream) {
    const float* x    = (const float*)d_in[0];
    const float* kern = (const float*)d_in[1];
    float* out        = (float*)d_out;

    dim3 grid(H, 16 * 3);   // 256 x 48 blocks
    dim3 block(256);        // one thread per input column
    bicubic_up4<<<grid, block, 0, stream>>>(x, kern, out);
}

// Round 2
// 202.100 us; speedup vs baseline: 1.0142x; 1.0142x over previous
//
#include <hip/hip_runtime.h>

#define H  256
#define W  256
#define S  4
#define OH (H * S)
#define OW (W * S)

// Thread = one input column (iw), a slab of 4 consecutive input rows.
// Each thread produces a 16(h) x 4(w) output tile via 16 float4 stores,
// each store perfectly lane-contiguous across the wave (64 x 16 B = 1 KiB).
__global__ __launch_bounds__(256) void bicubic_up4(
    const float* __restrict__ x, const float* __restrict__ kern,
    float* __restrict__ out)
{
    const int iw  = threadIdx.x;        // input column 0..255
    const int ihb = blockIdx.x * 4;     // first input row of this slab
    const int nc  = blockIdx.y;         // n*c 0..47

    // 16 filter taps (4 phases x 4 taps) — uniform address, scalarized
    float kk[16];
#pragma unroll
    for (int i = 0; i < 16; ++i) kk[i] = kern[i];

    const float* __restrict__ xp = x + (size_t)nc * (H * W);

    // horizontal taps: cols iw-1 .. iw+2 (replicate clamp)
    const int c0 = max(iw - 1, 0);
    const int c2 = min(iw + 1, W - 1);
    const int c3 = min(iw + 2, W - 1);
    const int cc[4] = { c0, iw, c2, c3 };

    // 7 rows cover the vertical windows of 4 input rows: ihb-1 .. ihb+5
    float p[7][4];
#pragma unroll
    for (int t = 0; t < 7; ++t) {
        int r = ihb - 1 + t;
        r = r < 0 ? 0 : (r > H - 1 ? H - 1 : r);
        const float* row = xp + r * W;
#pragma unroll
        for (int i = 0; i < 4; ++i) p[t][i] = row[cc[i]];
    }

    float* __restrict__ obase =
        out + ((size_t)nc * OH + (size_t)ihb * S) * OW + (size_t)iw * S;

#pragma unroll
    for (int q = 0; q < 4; ++q) {          // input row within the slab
#pragma unroll
        for (int kv = 0; kv < 4; ++kv) {   // vertical sub-pixel phase
            const float w0 = kk[kv * 4 + 0];
            const float w1 = kk[kv * 4 + 1];
            const float w2 = kk[kv * 4 + 2];
            const float w3 = kk[kv * 4 + 3];
            // vertical pass at the 4 tap columns (rows q..q+3 of p)
            const float v0 = p[q][0]*w0 + p[q+1][0]*w1 + p[q+2][0]*w2 + p[q+3][0]*w3;
            const float v1 = p[q][1]*w0 + p[q+1][1]*w1 + p[q+2][1]*w2 + p[q+3][1]*w3;
            const float v2 = p[q][2]*w0 + p[q+1][2]*w1 + p[q+2][2]*w2 + p[q+3][2]*w3;
            const float v3 = p[q][3]*w0 + p[q+1][3]*w1 + p[q+2][3]*w2 + p[q+3][3]*w3;
            // horizontal pass: 4 output phases -> one float4
            float4 o;
            o.x = v0*kk[0]  + v1*kk[1]  + v2*kk[2]  + v3*kk[3];
            o.y = v0*kk[4]  + v1*kk[5]  + v2*kk[6]  + v3*kk[7];
            o.z = v0*kk[8]  + v1*kk[9]  + v2*kk[10] + v3*kk[11];
            o.w = v0*kk[12] + v1*kk[13] + v2*kk[14] + v3*kk[15];
            *reinterpret_cast<float4*>(obase + ((size_t)q * S + kv) * OW) = o;
        }
    }
}

extern "C" void kernel_launch(void* const* d_in, const int* in_sizes, int n_in,
                              void* d_out, int out_size, void* d_ws, size_t ws_size,
                              hipStream_t stream) {
    const float* x    = (const float*)d_in[0];
    const float* kern = (const float*)d_in[1];
    float* out        = (float*)d_out;

    dim3 grid(H / 4, 16 * 3);   // 64 x 48 blocks
    dim3 block(256);            // one thread per input column
    bicubic_up4<<<grid, block, 0, stream>>>(x, kern, out);
}